// Round 1
// baseline (1205.208 us; speedup 1.0000x reference)
//
#include <hip/hip_runtime.h>
#include <cstdint>
#include <cstddef>

// ---- problem constants (fixed by setup_inputs) ----
#define B_   8
#define N_   8192
#define S_   2048
#define C1_  128
#define C2_  256
#define CIN_ 384      // C1 + C2
#define M_   65536    // B_ * N_
#define NOUT_ 512

// =====================================================================
// Kernel 1: 3-NN interpolation + concat -> x (M x 384)
// Replicates reference arithmetic: d = (|a|^2 + |b|^2) - 2*dot(a,b),
// dot as ascending fma chain; stable top-3 (lowest index wins ties).
// =====================================================================
__global__ __launch_bounds__(256) void interp_kernel(
    const float* __restrict__ xyz1, const float* __restrict__ xyz2,
    const float* __restrict__ points1, const float* __restrict__ points2,
    float* __restrict__ xout)
{
  __shared__ float sx[S_], sy[S_], sz[S_], sn[S_];
  __shared__ int   sIdx[256 * 3];
  __shared__ float sWgt[256 * 3];
  const int b  = blockIdx.y;
  const int n0 = blockIdx.x * 256;
  const int t  = threadIdx.x;

  // stage xyz2 (SoA) + norms
  const float* xb2 = xyz2 + (size_t)b * S_ * 3;
  for (int i = t; i < S_; i += 256) {
    float px = xb2[i * 3 + 0], py = xb2[i * 3 + 1], pz = xb2[i * 3 + 2];
    sx[i] = px; sy[i] = py; sz[i] = pz;
    sn[i] = __fadd_rn(__fadd_rn(__fmul_rn(px, px), __fmul_rn(py, py)), __fmul_rn(pz, pz));
  }
  __syncthreads();

  const int n = n0 + t;
  const float* p1 = xyz1 + ((size_t)b * N_ + n) * 3;
  const float ax = p1[0], ay = p1[1], az = p1[2];
  const float nrm1 = __fadd_rn(__fadd_rn(__fmul_rn(ax, ax), __fmul_rn(ay, ay)), __fmul_rn(az, az));

  float d0 = 3.0e38f, d1 = 3.0e38f, d2 = 3.0e38f;
  int   i0 = 0, i1 = 0, i2 = 0;
  #pragma unroll 4
  for (int j = 0; j < S_; ++j) {
    float ab = __fmaf_rn(az, sz[j], __fmaf_rn(ay, sy[j], __fmul_rn(ax, sx[j])));
    float d  = __fadd_rn(__fadd_rn(nrm1, sn[j]), __fmul_rn(-2.0f, ab));
    if (d < d2) {
      if (d < d1) {
        d2 = d1; i2 = i1;
        if (d < d0) { d1 = d0; i1 = i0; d0 = d; i0 = j; }
        else        { d1 = d;  i1 = j; }
      } else { d2 = d; i2 = j; }
    }
  }
  d0 = fmaxf(d0, 0.0f); d1 = fmaxf(d1, 0.0f); d2 = fmaxf(d2, 0.0f);
  float w0 = 1.0f / (d0 + 1e-8f);
  float w1 = 1.0f / (d1 + 1e-8f);
  float w2 = 1.0f / (d2 + 1e-8f);
  float wsum = __fadd_rn(__fadd_rn(w0, w1), w2);
  w0 /= wsum; w1 /= wsum; w2 /= wsum;
  sIdx[t * 3 + 0] = i0; sIdx[t * 3 + 1] = i1; sIdx[t * 3 + 2] = i2;
  sWgt[t * 3 + 0] = w0; sWgt[t * 3 + 1] = w1; sWgt[t * 3 + 2] = w2;
  __syncthreads();

  // phase 2: coalesced gather; thread = channel
  const float* p2b = points2 + (size_t)b * S_ * C2_;
  float* xb = xout + ((size_t)b * N_ + n0) * CIN_;
  for (int p = 0; p < 256; ++p) {
    int   j0 = sIdx[p * 3 + 0], j1 = sIdx[p * 3 + 1], j2 = sIdx[p * 3 + 2];
    float v0 = sWgt[p * 3 + 0], v1 = sWgt[p * 3 + 1], v2 = sWgt[p * 3 + 2];
    float f = __fadd_rn(__fadd_rn(__fmul_rn(p2b[(size_t)j0 * C2_ + t], v0),
                                  __fmul_rn(p2b[(size_t)j1 * C2_ + t], v1)),
                        __fmul_rn(p2b[(size_t)j2 * C2_ + t], v2));
    xb[(size_t)p * CIN_ + C1_ + t] = f;
  }
  // copy points1 into x[:, 0:128]
  const float* q1 = points1 + ((size_t)b * N_ + n0) * C1_;
  for (int it = 0; it < 128; ++it) {
    int idx = it * 256 + t;
    int p = idx >> 7, c = idx & 127;
    xb[(size_t)p * CIN_ + c] = q1[idx];
  }
}

// =====================================================================
// Kernel 2: fp32 tiled GEMM  Y[M,512] = A[M,K] * W[512,K]^T + bias
//  - optional on-the-fly BN+ReLU transform of A (for layer 2 input)
//  - fused per-channel sum / sumsq accumulation for BN stats
// Tile: BM=128, BN=128, BK=16; 256 threads; 8x8 microtile.
// =====================================================================
template <int K, bool BNIN>
__global__ __launch_bounds__(256) void gemm_kernel(
    const float* __restrict__ A, const float* __restrict__ W,
    const float* __restrict__ bias,
    const float* __restrict__ aScale, const float* __restrict__ aShift,
    float* __restrict__ Y,
    float* __restrict__ sumOut, float* __restrict__ sqOut)
{
  // stride 136 floats: keeps rows 16B-aligned for b128 reads
  __shared__ float As[16][136];
  __shared__ float Bs[16][136];
  __shared__ float sSc[BNIN ? K : 4];
  __shared__ float sSh[BNIN ? K : 4];
  __shared__ float sSum[128], sSq[128];

  const int t  = threadIdx.x;
  const int m0 = blockIdx.x * 128;
  const int n0 = blockIdx.y * 128;
  const int tx = t & 15, ty = t >> 4;

  if (BNIN) {
    for (int i = t; i < K; i += 256) { sSc[i] = aScale[i]; sSh[i] = aShift[i]; }
  }
  for (int i = t; i < 128; i += 256) { sSum[i] = 0.0f; sSq[i] = 0.0f; }
  __syncthreads();

  float acc[8][8];
  #pragma unroll
  for (int i = 0; i < 8; ++i)
    #pragma unroll
    for (int j = 0; j < 8; ++j) acc[i][j] = 0.0f;

  const float* Ab = A + (size_t)m0 * K;
  const float* Wb = W + (size_t)n0 * K;

  for (int kt = 0; kt < K; kt += 16) {
    #pragma unroll
    for (int i = 0; i < 2; ++i) {
      int idx4 = t + i * 256;          // 0..511
      int row  = idx4 >> 2;            // 0..127
      int k4   = (idx4 & 3) << 2;      // 0,4,8,12
      float4 va = *(const float4*)(Ab + (size_t)row * K + kt + k4);
      if (BNIN) {
        va.x = fmaxf(__fmaf_rn(va.x, sSc[kt + k4 + 0], sSh[kt + k4 + 0]), 0.0f);
        va.y = fmaxf(__fmaf_rn(va.y, sSc[kt + k4 + 1], sSh[kt + k4 + 1]), 0.0f);
        va.z = fmaxf(__fmaf_rn(va.z, sSc[kt + k4 + 2], sSh[kt + k4 + 2]), 0.0f);
        va.w = fmaxf(__fmaf_rn(va.w, sSc[kt + k4 + 3], sSh[kt + k4 + 3]), 0.0f);
      }
      As[k4 + 0][row] = va.x; As[k4 + 1][row] = va.y;
      As[k4 + 2][row] = va.z; As[k4 + 3][row] = va.w;
      float4 vw = *(const float4*)(Wb + (size_t)row * K + kt + k4);
      Bs[k4 + 0][row] = vw.x; Bs[k4 + 1][row] = vw.y;
      Bs[k4 + 2][row] = vw.z; Bs[k4 + 3][row] = vw.w;
    }
    __syncthreads();
    #pragma unroll
    for (int kk = 0; kk < 16; ++kk) {
      float a[8], bb[8];
      *(float4*)&a[0]  = *(const float4*)&As[kk][ty * 8];
      *(float4*)&a[4]  = *(const float4*)&As[kk][ty * 8 + 4];
      *(float4*)&bb[0] = *(const float4*)&Bs[kk][tx * 8];
      *(float4*)&bb[4] = *(const float4*)&Bs[kk][tx * 8 + 4];
      #pragma unroll
      for (int i = 0; i < 8; ++i)
        #pragma unroll
        for (int j = 0; j < 8; ++j)
          acc[i][j] = __fmaf_rn(a[i], bb[j], acc[i][j]);
    }
    __syncthreads();
  }

  // epilogue: bias, store, per-column stats
  float bj[8];
  #pragma unroll
  for (int j = 0; j < 8; ++j) bj[j] = bias[n0 + tx * 8 + j];

  float colS[8], colQ[8];
  #pragma unroll
  for (int j = 0; j < 8; ++j) { colS[j] = 0.0f; colQ[j] = 0.0f; }

  #pragma unroll
  for (int i = 0; i < 8; ++i) {
    int m = m0 + ty * 8 + i;
    float* yrow = Y + (size_t)m * NOUT_ + n0 + tx * 8;
    float vals[8];
    #pragma unroll
    for (int j = 0; j < 8; ++j) {
      float v = acc[i][j] + bj[j];
      vals[j] = v;
      colS[j] += v;
      colQ[j] = __fmaf_rn(v, v, colQ[j]);
    }
    *(float4*)&yrow[0] = make_float4(vals[0], vals[1], vals[2], vals[3]);
    *(float4*)&yrow[4] = make_float4(vals[4], vals[5], vals[6], vals[7]);
  }
  #pragma unroll
  for (int j = 0; j < 8; ++j) {
    atomicAdd(&sSum[tx * 8 + j], colS[j]);
    atomicAdd(&sSq[tx * 8 + j],  colQ[j]);
  }
  __syncthreads();
  for (int i = t; i < 128; i += 256) {
    atomicAdd(&sumOut[n0 + i], sSum[i]);
    atomicAdd(&sqOut[n0 + i],  sSq[i]);
  }
}

// =====================================================================
// Kernel 3: BN stats -> scale/shift
// =====================================================================
__global__ void finalize_kernel(const float* __restrict__ sum, const float* __restrict__ sq,
                                const float* __restrict__ g, const float* __restrict__ be,
                                float* __restrict__ scale, float* __restrict__ shift)
{
  int c = blockIdx.x * 256 + threadIdx.x;
  if (c >= 512) return;
  const float invM = 1.0f / 65536.0f;
  float mean = sum[c] * invM;
  float var  = fmaxf(sq[c] * invM - mean * mean, 0.0f);
  float rstd = rsqrtf(var + 1e-5f);
  float sc   = g[c] * rstd;
  scale[c] = sc;
  shift[c] = __fmaf_rn(-mean, sc, be[c]);
}

// =====================================================================
// Kernel 4: final BN+ReLU elementwise
// =====================================================================
__global__ __launch_bounds__(256) void bnrelu_kernel(
    const float* __restrict__ y, const float* __restrict__ scale,
    const float* __restrict__ shift, float* __restrict__ out)
{
  const size_t total4 = (size_t)M_ * NOUT_ / 4;
  for (size_t i4 = (size_t)blockIdx.x * 256 + threadIdx.x; i4 < total4;
       i4 += (size_t)gridDim.x * 256) {
    int c = ((int)(i4 & 127)) << 2;
    float4 v  = *(const float4*)(y + i4 * 4);
    float4 sc = *(const float4*)(scale + c);
    float4 sh = *(const float4*)(shift + c);
    float4 r;
    r.x = fmaxf(__fmaf_rn(v.x, sc.x, sh.x), 0.0f);
    r.y = fmaxf(__fmaf_rn(v.y, sc.y, sh.y), 0.0f);
    r.z = fmaxf(__fmaf_rn(v.z, sc.z, sh.z), 0.0f);
    r.w = fmaxf(__fmaf_rn(v.w, sc.w, sh.w), 0.0f);
    *(float4*)(out + i4 * 4) = r;
  }
}

// =====================================================================
extern "C" void kernel_launch(void* const* d_in, const int* in_sizes, int n_in,
                              void* d_out, int out_size, void* d_ws, size_t ws_size,
                              hipStream_t stream)
{
  const float* xyz1    = (const float*)d_in[0];
  const float* xyz2    = (const float*)d_in[1];
  const float* points1 = (const float*)d_in[2];
  const float* points2 = (const float*)d_in[3];
  const float* W1  = (const float*)d_in[4];
  const float* b1  = (const float*)d_in[5];
  const float* g1  = (const float*)d_in[6];
  const float* be1 = (const float*)d_in[7];
  const float* W2  = (const float*)d_in[8];
  const float* b2  = (const float*)d_in[9];
  const float* g2  = (const float*)d_in[10];
  const float* be2 = (const float*)d_in[11];

  float* ws = (float*)d_ws;
  // stats region: 4096 floats (16 KB)
  float* sum1 = ws + 0,    *sq1 = ws + 512,  *sc1 = ws + 1024, *sh1 = ws + 1536;
  float* sum2 = ws + 2048, *sq2 = ws + 2560, *sc2 = ws + 3072, *sh2 = ws + 3584;
  float* xbuf = ws + 4096;        // M x 384 (100.7 MB), dead after GEMM1
  float* y2   = ws + 4096;        // M x 512 (134.2 MB), aliases xbuf (GEMM2 output)
  float* y1   = (float*)d_out;    // M x 512, pre-BN layer-1 output lives in d_out

  hipMemsetAsync(d_ws, 0, 4096 * sizeof(float), stream);

  interp_kernel<<<dim3(N_ / 256, B_), 256, 0, stream>>>(xyz1, xyz2, points1, points2, xbuf);

  gemm_kernel<CIN_, false><<<dim3(M_ / 128, 4), 256, 0, stream>>>(
      xbuf, W1, b1, nullptr, nullptr, y1, sum1, sq1);

  finalize_kernel<<<2, 256, 0, stream>>>(sum1, sq1, g1, be1, sc1, sh1);

  gemm_kernel<512, true><<<dim3(M_ / 128, 4), 256, 0, stream>>>(
      y1, W2, b2, sc1, sh1, y2, sum2, sq2);

  finalize_kernel<<<2, 256, 0, stream>>>(sum2, sq2, g2, be2, sc2, sh2);

  bnrelu_kernel<<<2048, 256, 0, stream>>>(y2, sc2, sh2, (float*)d_out);
}